// Round 14
// baseline (26.297 us; speedup 1.0000x reference)
//
#include <hip/hip_runtime.h>
#include <math.h>

#define TB 2048
#define TK 128
#define TD 512
#define BR 8                 // rows per block
#define NBLK (TB / BR)       // 256 blocks = 1 per CU
#define NCH 8                // K' chunks (64 d each)
#define WSTR 136             // WB row stride in halves (128 + 8 pad)
#define XSTR 1032            // XA row stride in halves (1024 + 8 pad)

typedef _Float16 half8 __attribute__((ext_vector_type(8)));
typedef _Float16 half4 __attribute__((ext_vector_type(4)));
typedef float f32x4 __attribute__((ext_vector_type(4)));

// Single fused kernel. k' layout (paired, per 64-d chunk c):
//   k' = c*128 + j        -> A: x^2      B: 1/a        (d = c*64 + j)
//   k' = c*128 + 64 + j   -> A: x        B: -2c/a
// gemm = sum_d x^2/a - 2cx/a ;  dist_sq = gemm + e_k ;  e_k = sum c^2/a
// s_k = -0.5*(gemm + e_k + sum log a) ; logdet via log(prod a) (range-safe).
__global__ __launch_bounds__(512, 2) void gmm_kernel(
        const float* __restrict__ x, const float* __restrict__ C,
        const float* __restrict__ Dm, float* __restrict__ out) {
    __shared__ _Float16 XA[16][XSTR];   // 33 KB (rows 8..15 zeroed)
    __shared__ _Float16 WB[TK][WSTR];   // 34.8 KB (per-chunk B)
    __shared__ float offs[TK], es[TK];
    __shared__ float red_m[8][BR], red_s[8][BR], red_g[8][BR];
    __shared__ int   red_i[8][BR];

    const int tid = threadIdx.x;
    const int l = tid & 63;
    const int w = tid >> 6;
    const int l15 = l & 15;
    const int lg = l >> 4;
    const int b0 = blockIdx.x * BR;
    const int col = w * 16 + l15;

    // ---- zero XA rows 8..15 (incl. pads): 8*1032 halves = 1032 uint4 ----
    for (int i = tid; i < 8 * XSTR / 8; i += 512) {
        *reinterpret_cast<uint4*>(&XA[8][0] + (size_t)i * 8) = make_uint4(0, 0, 0, 0);
    }

    // ---- stage XA rows 0..7: 8 x 512 f32 -> paired f16 layout ----
    #pragma unroll
    for (int i = 0; i < 2; ++i) {
        int p = tid + i * 512;          // 0..1023 f4-groups
        int row = p >> 7;               // 0..7
        int dq = (p & 127) * 4;         // d base (mult of 4)
        float4 v = *reinterpret_cast<const float4*>(&x[(size_t)(b0 + row) * TD + dq]);
        int c = dq >> 6;
        int j = dq & 63;
        half4 hs, hi;
        hs[0] = (_Float16)(v.x * v.x); hs[1] = (_Float16)(v.y * v.y);
        hs[2] = (_Float16)(v.z * v.z); hs[3] = (_Float16)(v.w * v.w);
        hi[0] = (_Float16)v.x; hi[1] = (_Float16)v.y;
        hi[2] = (_Float16)v.z; hi[3] = (_Float16)v.w;
        *reinterpret_cast<half4*>(&XA[row][c * 128 + j]) = hs;
        *reinterpret_cast<half4*>(&XA[row][c * 128 + 64 + j]) = hi;
    }

    // ---- main loop: stage B chunk from Dm/C, then 4 MFMA k-steps ----
    const int pk = tid >> 2;            // param k (0..127)
    const int pg = tid & 3;             // d-subgroup (16 d each)
    float prodA = 1.f, esum = 0.f;
    f32x4 acc0 = (f32x4){0.f, 0.f, 0.f, 0.f};
    f32x4 acc1 = (f32x4){0.f, 0.f, 0.f, 0.f};

    for (int c = 0; c < NCH; ++c) {
        __syncthreads();   // WAR on WB (and XA/zeros visibility at c==0)
        #pragma unroll
        for (int q = 0; q < 4; ++q) {
            int d = c * 64 + pg * 16 + q * 4;
            float4 dv = *reinterpret_cast<const float4*>(&Dm[(size_t)pk * TD + d]);
            float4 cv = *reinterpret_cast<const float4*>(&C[(size_t)pk * TD + d]);
            float a0 = fabsf(dv.x) + 1e-8f, a1 = fabsf(dv.y) + 1e-8f;
            float a2 = fabsf(dv.z) + 1e-8f, a3 = fabsf(dv.w) + 1e-8f;
            float i0 = __builtin_amdgcn_rcpf(a0), i1 = __builtin_amdgcn_rcpf(a1);
            float i2 = __builtin_amdgcn_rcpf(a2), i3 = __builtin_amdgcn_rcpf(a3);
            prodA *= (a0 * a1) * (a2 * a3);
            float c0 = cv.x * i0, c1 = cv.y * i1, c2 = cv.z * i2, c3 = cv.w * i3;
            esum += (cv.x * c0 + cv.y * c1) + (cv.z * c2 + cv.w * c3);
            half4 hu, hc;
            hu[0] = (_Float16)i0; hu[1] = (_Float16)i1;
            hu[2] = (_Float16)i2; hu[3] = (_Float16)i3;
            hc[0] = (_Float16)(-2.f * c0); hc[1] = (_Float16)(-2.f * c1);
            hc[2] = (_Float16)(-2.f * c2); hc[3] = (_Float16)(-2.f * c3);
            int j = pg * 16 + q * 4;
            *reinterpret_cast<half4*>(&WB[pk][j]) = hu;
            *reinterpret_cast<half4*>(&WB[pk][64 + j]) = hc;
        }
        __syncthreads();   // WB visible
        {
            int ko0 = lg * 8;           // ks=0
            int ko1 = 32 + lg * 8;      // ks=1
            int ko2 = 64 + lg * 8;      // ks=2
            int ko3 = 96 + lg * 8;      // ks=3
            half8 a0 = *reinterpret_cast<const half8*>(&XA[l15][c * 128 + ko0]);
            half8 bb0 = *reinterpret_cast<const half8*>(&WB[col][ko0]);
            half8 a1 = *reinterpret_cast<const half8*>(&XA[l15][c * 128 + ko1]);
            half8 bb1 = *reinterpret_cast<const half8*>(&WB[col][ko1]);
            half8 a2 = *reinterpret_cast<const half8*>(&XA[l15][c * 128 + ko2]);
            half8 bb2 = *reinterpret_cast<const half8*>(&WB[col][ko2]);
            half8 a3 = *reinterpret_cast<const half8*>(&XA[l15][c * 128 + ko3]);
            half8 bb3 = *reinterpret_cast<const half8*>(&WB[col][ko3]);
            acc0 = __builtin_amdgcn_mfma_f32_16x16x32_f16(a0, bb0, acc0, 0, 0, 0);
            acc1 = __builtin_amdgcn_mfma_f32_16x16x32_f16(a1, bb1, acc1, 0, 0, 0);
            acc0 = __builtin_amdgcn_mfma_f32_16x16x32_f16(a2, bb2, acc0, 0, 0, 0);
            acc1 = __builtin_amdgcn_mfma_f32_16x16x32_f16(a3, bb3, acc1, 0, 0, 0);
        }
    }
    f32x4 acc = acc0 + acc1;

    // ---- per-k param reduction: combine the 4 pg-threads (same wave) ----
    esum += __shfl_xor(esum, 1, 64);
    esum += __shfl_xor(esum, 2, 64);
    prodA *= __shfl_xor(prodA, 1, 64);
    prodA *= __shfl_xor(prodA, 2, 64);
    if (pg == 0) {
        float lgd = logf(prodA);
        offs[pk] = -0.5f * (esum + lgd);
        es[pk] = esum;
    }
    __syncthreads();

    // ---- epilogue: per-wave softmax partials over its 16 cols ----
    const float offc = offs[col];
    float sv[4], bv[4], bg[4], ps[4];
    int bi[4];
    #pragma unroll
    for (int e = 0; e < 4; ++e) {
        sv[e] = fmaf(-0.5f, acc[e], offc);
        bv[e] = sv[e]; bi[e] = col; bg[e] = acc[e];
    }
    #pragma unroll
    for (int msk = 1; msk <= 8; msk <<= 1) {
        #pragma unroll
        for (int e = 0; e < 4; ++e) {
            float ov = __shfl_xor(bv[e], msk, 64);
            int   oi = __shfl_xor(bi[e], msk, 64);
            float og = __shfl_xor(bg[e], msk, 64);
            if (ov > bv[e] || (ov == bv[e] && oi < bi[e])) {
                bv[e] = ov; bi[e] = oi; bg[e] = og;
            }
        }
    }
    #pragma unroll
    for (int e = 0; e < 4; ++e) ps[e] = expf(sv[e] - bv[e]);
    #pragma unroll
    for (int msk = 1; msk <= 8; msk <<= 1)
        #pragma unroll
        for (int e = 0; e < 4; ++e) ps[e] += __shfl_xor(ps[e], msk, 64);

    if (l15 == 0) {
        #pragma unroll
        for (int e = 0; e < 4; ++e) {
            int r = lg * 4 + e;
            if (r < BR) {
                red_m[w][r] = bv[e];
                red_s[w][r] = ps[e];
                red_i[w][r] = bi[e];
                red_g[w][r] = bg[e];
            }
        }
    }
    __syncthreads();

    // ---- combine 8 waves -> lse ; write resp ----
    const float LOGC = -18.420680743952367f;  // ln(1e-8)
    #pragma unroll
    for (int e = 0; e < 4; ++e) {
        int r = lg * 4 + e;
        if (r < BR) {
            float M = red_m[0][r];
            #pragma unroll
            for (int w2 = 1; w2 < 8; ++w2) M = fmaxf(M, red_m[w2][r]);
            float S = 0.f;
            #pragma unroll
            for (int w2 = 0; w2 < 8; ++w2) S += red_s[w2][r] * expf(red_m[w2][r] - M);
            float lse = logf(S) + M;
            out[(size_t)(b0 + r) * TK + col] = fmaxf(sv[e] - lse, LOGC);
        }
    }

    // ---- dist: global argmax over waves ----
    if (w == 0 && l15 == 0) {
        #pragma unroll
        for (int e = 0; e < 4; ++e) {
            int r = lg * 4 + e;
            if (r < BR) {
                float v = red_m[0][r]; int ki = red_i[0][r]; float g = red_g[0][r];
                #pragma unroll
                for (int w2 = 1; w2 < 8; ++w2) {
                    float v2 = red_m[w2][r]; int i2 = red_i[w2][r];
                    if (v2 > v || (v2 == v && i2 < ki)) { v = v2; ki = i2; g = red_g[w2][r]; }
                }
                out[(size_t)TB * TK + b0 + r] = sqrtf(fmaxf(g + es[ki], 0.f));
            }
        }
    }
}

// ---------------------------------------------------------------------------
extern "C" void kernel_launch(void* const* d_in, const int* in_sizes, int n_in,
                              void* d_out, int out_size, void* d_ws, size_t ws_size,
                              hipStream_t stream) {
    const float* x  = (const float*)d_in[0];
    const float* C  = (const float*)d_in[1];
    const float* Dm = (const float*)d_in[2];
    float* out = (float*)d_out;

    gmm_kernel<<<NBLK, 512, 0, stream>>>(x, C, Dm, out);
}

// Round 15
// 23.706 us; speedup vs baseline: 1.1093x; 1.1093x over previous
//
#include <hip/hip_runtime.h>
#include <math.h>

#define TB 2048
#define TK 128
#define TD 512
#define BR 8                 // real rows per block (MFMA M=16, rows 8..15 zero)
#define NBLK (TB / BR)       // 256 blocks = 1 per CU
#define NKS 32               // K' = 1024 = 32 MFMA k-steps of 32

typedef _Float16 half8 __attribute__((ext_vector_type(8)));
typedef float f32x4 __attribute__((ext_vector_type(4)));

// k' mapping (both operands): k' = 2*d + t ; t=0 -> A:x^2, B:1/a ; t=1 -> A:x, B:-2c/a
// Fragment record (ks, lane): col/row = lane&15, d0 = ks*16 + (lane>>4)*4,
//   contents = {v(d0,t0), v(d0,t1), v(d0+1,t0), ..., v(d0+3,t1)}  (8 halves, 16B)
// ws: Wfrag f16[8 cb][32 ks][64 lane][8] = 256 KB ; off f32[128] ; ebuf f32[128]

// ---------------------------------------------------------------------------
// prep: one block per class k, 128 threads; thread t covers d0 = (t>>2)*16+(t&3)*4.
// Writes the B fragment record slice for col k; reduces e_k and logdet.
// ---------------------------------------------------------------------------
__global__ __launch_bounds__(128) void prep_kernel(const float* __restrict__ C,
        const float* __restrict__ Dm, _Float16* __restrict__ Wfrag,
        float* __restrict__ off, float* __restrict__ ebuf) {
    __shared__ float sE[2], sL[2];
    const int k = blockIdx.x;
    const int t = threadIdx.x;
    const int ks = t >> 2, lg = t & 3;
    const int d0 = ks * 16 + lg * 4;

    float4 dv = *reinterpret_cast<const float4*>(&Dm[(size_t)k * TD + d0]);
    float4 cv = *reinterpret_cast<const float4*>(&C[(size_t)k * TD + d0]);
    float a0 = fabsf(dv.x) + 1e-8f, a1 = fabsf(dv.y) + 1e-8f;
    float a2 = fabsf(dv.z) + 1e-8f, a3 = fabsf(dv.w) + 1e-8f;
    float i0 = 1.f / a0, i1 = 1.f / a1, i2 = 1.f / a2, i3 = 1.f / a3;
    float c0 = cv.x * i0, c1 = cv.y * i1, c2 = cv.z * i2, c3 = cv.w * i3;

    half8 h;
    h[0] = (_Float16)i0; h[1] = (_Float16)(-2.f * c0);
    h[2] = (_Float16)i1; h[3] = (_Float16)(-2.f * c1);
    h[4] = (_Float16)i2; h[5] = (_Float16)(-2.f * c2);
    h[6] = (_Float16)i3; h[7] = (_Float16)(-2.f * c3);
    *reinterpret_cast<half8*>(
        &Wfrag[(((size_t)(k >> 4) * NKS + ks) * 64 + lg * 16 + (k & 15)) * 8]) = h;

    float es = (cv.x * c0 + cv.y * c1) + (cv.z * c2 + cv.w * c3);
    float ls = logf((a0 * a1) * (a2 * a3));   // a in [0.9,1.1]: product safe
    #pragma unroll
    for (int m = 1; m <= 32; m <<= 1) {
        es += __shfl_xor(es, m, 64);
        ls += __shfl_xor(ls, m, 64);
    }
    if ((t & 63) == 0) { sE[t >> 6] = es; sL[t >> 6] = ls; }
    __syncthreads();
    if (t == 0) {
        float E = sE[0] + sE[1], L = sL[0] + sL[1];
        off[k] = -0.5f * (E + L);
        ebuf[k] = E;
    }
}

// ---------------------------------------------------------------------------
// main: 256 blocks x 512 thr (8 waves). Block = 8 rows x 128 cols, full K'.
// Wave w owns cols [w*16, w*16+16): 32 MFMA; B streamed from global in
// fragment order (1KB contiguous per wave-load), A from LDS in fragment
// order (conflict-free ds_read_b128). Epilogue: in-block softmax+argmax+dist.
// ---------------------------------------------------------------------------
__global__ __launch_bounds__(512) void gmm_kernel(const float* __restrict__ x,
        const _Float16* __restrict__ Wfrag, const float* __restrict__ off,
        const float* __restrict__ ebuf, float* __restrict__ out) {
    __shared__ __align__(16) _Float16 XAf[NKS * 64 * 8];   // 32 KB, fragment order
    __shared__ float red_m[8][BR], red_s[8][BR], red_g[8][BR];
    __shared__ int   red_i[8][BR];

    const int tid = threadIdx.x;
    const int l = tid & 63;
    const int w = tid >> 6;
    const int l15 = l & 15;
    const int lg = l >> 4;
    const int b0 = blockIdx.x * BR;
    const int col = w * 16 + l15;

    // ---- stage A fragments: 2048 records, 4 per thread, contiguous writes ----
    #pragma unroll
    for (int i = 0; i < 4; ++i) {
        int rec = tid + i * 512;              // 0..2047
        int ks = rec >> 6;
        int lr = rec & 63;
        int row = lr & 15;
        int lgr = lr >> 4;
        half8 h = (half8){0, 0, 0, 0, 0, 0, 0, 0};
        if (row < BR) {
            int d0 = ks * 16 + lgr * 4;
            float4 v = *reinterpret_cast<const float4*>(
                &x[(size_t)(b0 + row) * TD + d0]);
            h[0] = (_Float16)(v.x * v.x); h[1] = (_Float16)v.x;
            h[2] = (_Float16)(v.y * v.y); h[3] = (_Float16)v.y;
            h[4] = (_Float16)(v.z * v.z); h[5] = (_Float16)v.z;
            h[6] = (_Float16)(v.w * v.w); h[7] = (_Float16)v.w;
        }
        *reinterpret_cast<half8*>(&XAf[(size_t)rec * 8]) = h;
    }
    __syncthreads();

    // ---- GEMM: 32 MFMA, B global (L2-hot, coalesced), A LDS (conflict-free) ----
    const _Float16* wf = Wfrag + (size_t)w * NKS * 64 * 8;
    f32x4 acc0 = (f32x4){0.f, 0.f, 0.f, 0.f};
    f32x4 acc1 = (f32x4){0.f, 0.f, 0.f, 0.f};
    #pragma unroll 8
    for (int ks = 0; ks < NKS; ks += 2) {
        half8 bv0 = *reinterpret_cast<const half8*>(&wf[((size_t)ks * 64 + l) * 8]);
        half8 av0 = *reinterpret_cast<const half8*>(&XAf[((size_t)ks * 64 + l) * 8]);
        half8 bv1 = *reinterpret_cast<const half8*>(&wf[((size_t)(ks + 1) * 64 + l) * 8]);
        half8 av1 = *reinterpret_cast<const half8*>(&XAf[((size_t)(ks + 1) * 64 + l) * 8]);
        acc0 = __builtin_amdgcn_mfma_f32_16x16x32_f16(av0, bv0, acc0, 0, 0, 0);
        acc1 = __builtin_amdgcn_mfma_f32_16x16x32_f16(av1, bv1, acc1, 0, 0, 0);
    }
    f32x4 acc = acc0 + acc1;   // gemm[row=lg*4+e][col] = sum x^2/a - 2cx/a

    // ---- epilogue: per-wave softmax partials over its 16 cols ----
    const float offc = off[col];
    float sv[4], bv[4], bg[4], ps[4];
    int bi[4];
    #pragma unroll
    for (int e = 0; e < 4; ++e) {
        sv[e] = fmaf(-0.5f, acc[e], offc);
        bv[e] = sv[e]; bi[e] = col; bg[e] = acc[e];
    }
    #pragma unroll
    for (int msk = 1; msk <= 8; msk <<= 1) {
        #pragma unroll
        for (int e = 0; e < 4; ++e) {
            float ov = __shfl_xor(bv[e], msk, 64);
            int   oi = __shfl_xor(bi[e], msk, 64);
            float og = __shfl_xor(bg[e], msk, 64);
            if (ov > bv[e] || (ov == bv[e] && oi < bi[e])) {
                bv[e] = ov; bi[e] = oi; bg[e] = og;
            }
        }
    }
    #pragma unroll
    for (int e = 0; e < 4; ++e) ps[e] = expf(sv[e] - bv[e]);
    #pragma unroll
    for (int msk = 1; msk <= 8; msk <<= 1)
        #pragma unroll
        for (int e = 0; e < 4; ++e) ps[e] += __shfl_xor(ps[e], msk, 64);

    if (l15 == 0) {
        #pragma unroll
        for (int e = 0; e < 4; ++e) {
            int r = lg * 4 + e;
            if (r < BR) {
                red_m[w][r] = bv[e];
                red_s[w][r] = ps[e];
                red_i[w][r] = bi[e];
                red_g[w][r] = bg[e];
            }
        }
    }
    __syncthreads();

    // ---- combine 8 waves -> lse ; write resp ----
    const float LOGC = -18.420680743952367f;  // ln(1e-8)
    #pragma unroll
    for (int e = 0; e < 4; ++e) {
        int r = lg * 4 + e;
        if (r < BR) {
            float M = red_m[0][r];
            #pragma unroll
            for (int w2 = 1; w2 < 8; ++w2) M = fmaxf(M, red_m[w2][r]);
            float S = 0.f;
            #pragma unroll
            for (int w2 = 0; w2 < 8; ++w2) S += red_s[w2][r] * expf(red_m[w2][r] - M);
            float lse = logf(S) + M;
            out[(size_t)(b0 + r) * TK + col] = fmaxf(sv[e] - lse, LOGC);
        }
    }

    // ---- dist: global argmax over waves, wave-0 leaders write ----
    if (w == 0 && l15 == 0) {
        #pragma unroll
        for (int e = 0; e < 4; ++e) {
            int r = lg * 4 + e;
            if (r < BR) {
                float v = red_m[0][r]; int ki = red_i[0][r]; float g = red_g[0][r];
                #pragma unroll
                for (int w2 = 1; w2 < 8; ++w2) {
                    float v2 = red_m[w2][r]; int i2 = red_i[w2][r];
                    if (v2 > v || (v2 == v && i2 < ki)) { v = v2; ki = i2; g = red_g[w2][r]; }
                }
                out[(size_t)TB * TK + b0 + r] = sqrtf(fmaxf(g + ebuf[ki], 0.f));
            }
        }
    }
}

// ---------------------------------------------------------------------------
extern "C" void kernel_launch(void* const* d_in, const int* in_sizes, int n_in,
                              void* d_out, int out_size, void* d_ws, size_t ws_size,
                              hipStream_t stream) {
    const float* x  = (const float*)d_in[0];
    const float* C  = (const float*)d_in[1];
    const float* Dm = (const float*)d_in[2];
    float* out = (float*)d_out;

    _Float16* Wfrag = (_Float16*)d_ws;                                 // 256 KB
    float* off  = (float*)((char*)d_ws + (size_t)TK * 2 * TD * 2);     // 512 B
    float* ebuf = off + TK;                                            // 512 B

    prep_kernel<<<TK, 128, 0, stream>>>(C, Dm, Wfrag, off, ebuf);
    gmm_kernel<<<NBLK, 512, 0, stream>>>(x, Wfrag, off, ebuf, out);
}